// Round 8
// baseline (491.055 us; speedup 1.0000x reference)
//
#include <hip/hip_runtime.h>
#include <math.h>

#define NB_TOK 16384
#define DM     1024
#define NEXP   8
#define KIN    1536
#define SECBIT 0x40000000
#define TOKMSK 0x3FFFFFFF

typedef __attribute__((ext_vector_type(8))) short          short8;
typedef __attribute__((ext_vector_type(8))) unsigned short ushort8;
typedef __attribute__((ext_vector_type(4))) unsigned short ushort4v;
typedef __attribute__((ext_vector_type(8))) _Float16       half8;
typedef __attribute__((ext_vector_type(4))) float          floatx4;

#define AS1U(p) ((const __attribute__((address_space(1))) unsigned int*)(p))
#define AS3U(p) ((__attribute__((address_space(3))) unsigned int*)(p))

__device__ __forceinline__ float gelu_f(float x) {
    return 0.5f * x * (1.0f + erff(x * 0.70710678118654752440f));
}

__device__ __forceinline__ unsigned short f2bf(float x) {
    unsigned u = __float_as_uint(x);
    u = (u + 0x7FFF + ((u >> 16) & 1)) >> 16;   // RNE
    return (unsigned short)u;
}

__device__ __forceinline__ void split_h16(float x, unsigned short& hi, unsigned short& lo) {
    _Float16 h = (_Float16)x;
    float r = x - (float)h;
    _Float16 l = (_Float16)r;
    hi = *(unsigned short*)&h;
    lo = *(unsigned short*)&l;
}

// ---------------- feature split: concat fp32 -> fp16 hi/lo [tok][KIN], A scaled x4 ----------------
__global__ __launch_bounds__(256) void k_splitA(
    const float* __restrict__ f0, const float* __restrict__ f1,
    const float* __restrict__ f2, unsigned short* __restrict__ Ah,
    unsigned short* __restrict__ Al)
{
    const int i4  = blockIdx.x * 256 + threadIdx.x;
    const int tok = i4 / (KIN / 4);
    const int k   = (i4 % (KIN / 4)) * 4;
    const float* src; int ld, c;
    if (k < 768)       { src = f0; ld = 768; c = k; }
    else if (k < 1280) { src = f1; ld = 512; c = k - 768; }
    else               { src = f2; ld = 256; c = k - 1280; }
    const float4 v = *(const float4*)(src + (size_t)tok * ld + c);
    const float* vp = (const float*)&v;
    ushort4v hi, lo;
#pragma unroll
    for (int j = 0; j < 4; ++j) {
        unsigned short h, l;
        split_h16(vp[j] * 4.0f, h, l);
        hi[j] = h; lo[j] = l;
    }
    *(ushort4v*)(Ah + (size_t)tok * KIN + k) = hi;
    *(ushort4v*)(Al + (size_t)tok * KIN + k) = lo;
}

// ---------------- Ws fp32 [k][n] -> fp16 hi/lo transposed [n][k], scaled x256 ----------------
__global__ __launch_bounds__(256) void k_splitB(
    const float* __restrict__ Ws, unsigned short* __restrict__ BhT,
    unsigned short* __restrict__ BlT)
{
    __shared__ float s[32][33];
    const int n0 = blockIdx.x * 32, k0 = blockIdx.y * 32;
    const int c  = threadIdx.x & 31, r = threadIdx.x >> 5;
#pragma unroll
    for (int p = 0; p < 4; ++p)
        s[r + p * 8][c] = Ws[(size_t)(k0 + r + p * 8) * DM + n0 + c];
    __syncthreads();
#pragma unroll
    for (int p = 0; p < 4; ++p) {
        const int n = r + p * 8;
        unsigned short h, l;
        split_h16(s[c][n] * 256.0f, h, l);
        BhT[(size_t)(n0 + n) * KIN + k0 + c] = h;
        BlT[(size_t)(n0 + n) * KIN + k0 + c] = l;
    }
}

// ---------------- shared GEMM via fp16x2-split MFMA; XCD-locality swizzled grid ----------------
__global__ __launch_bounds__(256) void k_shared_mfma(
    const unsigned short* __restrict__ Ah, const unsigned short* __restrict__ Al,
    const unsigned short* __restrict__ BhT, const unsigned short* __restrict__ BlT,
    const float* __restrict__ bs, float* __restrict__ h)
{
    __shared__ unsigned short ldsAh[128][64];
    __shared__ unsigned short ldsAl[128][64];
    __shared__ unsigned short ldsBh[128][64];
    __shared__ unsigned short ldsBl[128][64];

    const int t    = threadIdx.x;
    const int lane = t & 63;
    const int wave = t >> 6;
    // swizzle: 8 col-tiles of one row-panel share an XCD (id%8 = row%8) and are
    // consecutive within the XCD's dispatch window -> A-panel L2 reuse.
    const int bid  = blockIdx.x;
    const int brow = ((bid >> 6) << 3) + (bid & 7);   // 0..127
    const int bcol = (bid >> 3) & 7;                  // 0..7
    const int row0 = brow * 128;
    const int n0g  = bcol * 128;

    const int srow = t >> 3;
    const int g    = (t & 7) ^ (srow & 7);
    const unsigned short *sAh[4], *sAl[4], *sBh[4], *sBl[4];
#pragma unroll
    for (int q = 0; q < 4; ++q) {
        const size_t ra = (size_t)(row0 + q * 32 + srow) * KIN + g * 8;
        const size_t rb = (size_t)(n0g + q * 32 + srow) * KIN + g * 8;
        sAh[q] = Ah + ra; sAl[q] = Al + ra;
        sBh[q] = BhT + rb; sBl[q] = BlT + rb;
    }

    const int grp = lane >> 4;
    int offA[2][4], offB[2][4];
#pragma unroll
    for (int ks = 0; ks < 2; ++ks)
#pragma unroll
        for (int m = 0; m < 4; ++m) {
            const int rA = ((wave >> 1) * 64) + m * 16 + (lane & 15);
            const int rB = ((wave & 1) * 64) + m * 16 + (lane & 15);
            const int c  = ks * 4 + grp;
            offA[ks][m] = rA * 128 + (((c ^ (rA & 7)) & 7) << 4);
            offB[ks][m] = rB * 128 + (((c ^ (rB & 7)) & 7) << 4);
        }

    floatx4 acc[4][4];
#pragma unroll
    for (int m = 0; m < 4; ++m)
#pragma unroll
        for (int n = 0; n < 4; ++n) acc[m][n] = (floatx4){0.f, 0.f, 0.f, 0.f};

    const char* lAh = (const char*)&ldsAh[0][0];
    const char* lAl = (const char*)&ldsAl[0][0];
    const char* lBh = (const char*)&ldsBh[0][0];
    const char* lBl = (const char*)&ldsBl[0][0];

    for (int kt = 0; kt < KIN / 64; ++kt) {
        const int k0 = kt * 64;
        __syncthreads();
#pragma unroll
        for (int q = 0; q < 4; ++q) {
            const int dst = q * 4096 + wave * 1024;
            __builtin_amdgcn_global_load_lds(AS1U(sAh[q] + k0), AS3U((char*)lAh + dst), 16, 0, 0);
            __builtin_amdgcn_global_load_lds(AS1U(sAl[q] + k0), AS3U((char*)lAl + dst), 16, 0, 0);
            __builtin_amdgcn_global_load_lds(AS1U(sBh[q] + k0), AS3U((char*)lBh + dst), 16, 0, 0);
            __builtin_amdgcn_global_load_lds(AS1U(sBl[q] + k0), AS3U((char*)lBl + dst), 16, 0, 0);
        }
        __syncthreads();
#pragma unroll
        for (int ks = 0; ks < 2; ++ks) {
            half8 ah[4], al[4], bh[4], bl[4];
#pragma unroll
            for (int m = 0; m < 4; ++m) {
                ah[m] = *(const half8*)(lAh + offA[ks][m]);
                al[m] = *(const half8*)(lAl + offA[ks][m]);
            }
#pragma unroll
            for (int n = 0; n < 4; ++n) {
                bh[n] = *(const half8*)(lBh + offB[ks][n]);
                bl[n] = *(const half8*)(lBl + offB[ks][n]);
            }
#pragma unroll
            for (int m = 0; m < 4; ++m)
#pragma unroll
                for (int n = 0; n < 4; ++n) {
                    acc[m][n] = __builtin_amdgcn_mfma_f32_16x16x32_f16(ah[m], bh[n], acc[m][n], 0, 0, 0);
                    acc[m][n] = __builtin_amdgcn_mfma_f32_16x16x32_f16(ah[m], bl[n], acc[m][n], 0, 0, 0);
                    acc[m][n] = __builtin_amdgcn_mfma_f32_16x16x32_f16(al[m], bh[n], acc[m][n], 0, 0, 0);
                }
        }
    }

    const int wr = wave >> 1, wc = wave & 1;
#pragma unroll
    for (int n = 0; n < 4; ++n) {
        const int col  = n0g + wc * 64 + n * 16 + (lane & 15);
        const float bias = bs[col];
#pragma unroll
        for (int m = 0; m < 4; ++m) {
            const int rbase = row0 + wr * 64 + m * 16 + (lane >> 4) * 4;
#pragma unroll
            for (int reg = 0; reg < 4; ++reg) {
                const float o = gelu_f(acc[m][n][reg] * (1.0f / 1024.0f) + bias);
                h[(size_t)(rbase + reg) * DM + col] = o;
            }
        }
    }
}

// ---------------- W_experts fp32 [e][k][n] -> bf16 transposed [e][n][k] ----------------
__global__ __launch_bounds__(256) void k_wt_bf16(
    const float* __restrict__ We, unsigned short* __restrict__ WeT)
{
    __shared__ float s[32][33];
    const int e  = blockIdx.z;
    const int k0 = blockIdx.y * 32, n0 = blockIdx.x * 32;
    const int c  = threadIdx.x & 31, r = threadIdx.x >> 5;
    const float* W = We + ((size_t)e << 20);
#pragma unroll
    for (int p = 0; p < 4; ++p) {
        const int k = r + p * 8;
        s[k][c] = W[(size_t)(k0 + k) * DM + n0 + c];
    }
    __syncthreads();
#pragma unroll
    for (int p = 0; p < 4; ++p) {
        const int n = r + p * 8;
        WeT[((size_t)e << 20) + (size_t)(n0 + n) * DM + k0 + c] = f2bf(s[c][n]);
    }
}

// ---------------- gate top-2: fp32 exact, NO atomics ----------------
__global__ __launch_bounds__(256) void k_gate_topk(
    const float* __restrict__ h, const float* __restrict__ Wg,
    const float* __restrict__ bg, int* __restrict__ eidx,
    float2* __restrict__ w01)
{
    const int lane = threadIdx.x & 63;
    const int wv   = threadIdx.x >> 6;
    const int tok  = blockIdx.x * 4 + wv;
    const float* hr = h + (size_t)tok * DM;
    float acc[NEXP];
#pragma unroll
    for (int e = 0; e < NEXP; ++e) acc[e] = 0.f;
    for (int j = 0; j < DM / 64; ++j) {
        const float hv = hr[lane + 64 * j];
        const float* wr = Wg + (size_t)(lane + 64 * j) * NEXP;
#pragma unroll
        for (int e = 0; e < NEXP; ++e) acc[e] = fmaf(hv, wr[e], acc[e]);
    }
#pragma unroll
    for (int off = 32; off > 0; off >>= 1) {
#pragma unroll
        for (int e = 0; e < NEXP; ++e) acc[e] += __shfl_xor(acc[e], off, 64);
    }
    if (lane == 0) {
        float lg[NEXP];
        float mx = -1e30f;
#pragma unroll
        for (int e = 0; e < NEXP; ++e) { lg[e] = acc[e] + bg[e]; mx = fmaxf(mx, lg[e]); }
        float p[NEXP]; float s = 0.f;
#pragma unroll
        for (int e = 0; e < NEXP; ++e) { p[e] = expf(lg[e] - mx); s += p[e]; }
        const float inv = 1.f / s;
        int i0 = 0;
#pragma unroll
        for (int e = 1; e < NEXP; ++e) if (p[e] > p[i0]) i0 = e;
        int i1 = (i0 == 0) ? 1 : 0;
#pragma unroll
        for (int e = 0; e < NEXP; ++e) if (e != i0 && p[e] > p[i1]) i1 = e;
        eidx[tok] = i0 | (i1 << 8);
        w01[tok]  = make_float2(p[i0] * inv, p[i1] * inv);
    }
}

// ---------------- bucketize: block-aggregated; secondary slots tagged with SECBIT ----------------
__global__ __launch_bounds__(256) void k_bucket(
    const int* __restrict__ eidx, const float2* __restrict__ w01,
    int* __restrict__ counts, int* __restrict__ btok, float* __restrict__ bwgt)
{
    __shared__ int lcnt[NEXP], lbase[NEXP];
    const int tid = threadIdx.x;
    const int tok = blockIdx.x * 256 + tid;
    if (tid < NEXP) lcnt[tid] = 0;
    __syncthreads();
    const int ee = eidx[tok];
    const float2 w = w01[tok];
    const int e0 = ee & 0xff, e1 = ee >> 8;
    const int l0 = atomicAdd(&lcnt[e0], 1);
    const int l1 = atomicAdd(&lcnt[e1], 1);
    __syncthreads();
    if (tid < NEXP) lbase[tid] = atomicAdd(&counts[tid], lcnt[tid]);
    __syncthreads();
    const int s0 = lbase[e0] + l0;
    btok[e0 * NB_TOK + s0] = tok;           bwgt[e0 * NB_TOK + s0] = w.x;   // primary
    const int s1 = lbase[e1] + l1;
    btok[e1 * NB_TOK + s1] = tok | SECBIT;  bwgt[e1 * NB_TOK + s1] = w.y;   // secondary
}

// ---------------- exclusive prefix of counts -> compact bases ----------------
__global__ void k_prefix(const int* __restrict__ counts, int* __restrict__ basep)
{
    if (threadIdx.x == 0) {
        int r = 0;
#pragma unroll
        for (int e = 0; e < NEXP; ++e) { basep[e] = r; r += counts[e]; }
    }
}

// ---------------- gather: compact routed rows h(fp32) -> hbfc(bf16), sequential A ----------------
__global__ __launch_bounds__(256) void k_gather(
    const float* __restrict__ h, const int* __restrict__ btok,
    const int* __restrict__ basep, unsigned short* __restrict__ hbfc)
{
    const int g = blockIdx.x;            // 0..32767 (total routed rows == 2*NB_TOK)
    int e = 0;
#pragma unroll
    for (int i = 1; i < NEXP; ++i) if (g >= basep[i]) e = i;
    const int idx = g - basep[e];
    const int tok = btok[e * NB_TOK + idx] & TOKMSK;
    const int c   = threadIdx.x * 4;
    const float4 v = *(const float4*)(h + (size_t)tok * DM + c);
    ushort4v o;
    o[0] = f2bf(v.x); o[1] = f2bf(v.y); o[2] = f2bf(v.z); o[3] = f2bf(v.w);
    *(ushort4v*)(hbfc + (size_t)g * DM + c) = o;
}

// ---------------- expert GEMM: bf16 MFMA, sequential compacted A, 2-phase dbuf ----------------
#define EXP_STAGE(b, k0)                                                                              \
    {                                                                                                 \
        char* lAw = (char*)&ldsA[b][0][0];                                                            \
        char* lBw = (char*)&ldsB[b][0][0];                                                            \
        _Pragma("unroll")                                                                             \
        for (int q = 0; q < 4; ++q) {                                                                 \
            __builtin_amdgcn_global_load_lds(AS1U(srcA[q] + (k0)), AS3U(lAw + q * 4096 + wave * 1024), 16, 0, 0); \
            __builtin_amdgcn_global_load_lds(AS1U(srcB[q] + (k0)), AS3U(lBw + q * 4096 + wave * 1024), 16, 0, 0); \
        }                                                                                             \
    }

__global__ __launch_bounds__(256) void k_expert_mfma(
    const unsigned short* __restrict__ hbfc,
    const unsigned short* __restrict__ WeT,
    const float* __restrict__ bexp,
    const int* __restrict__ counts, const int* __restrict__ basep,
    const int* __restrict__ btok, const float* __restrict__ bwgt,
    float* __restrict__ stage2, float* __restrict__ out)
{
    const int e    = blockIdx.z;
    const int cnt  = counts[e];
    const int row0 = blockIdx.y * 128;
    if (row0 >= cnt) return;
    const int gb   = basep[e];

    __shared__ unsigned short ldsA[2][128][64];
    __shared__ unsigned short ldsB[2][128][64];
    __shared__ int   sTok[128];
    __shared__ float sWt[128];

    const int t    = threadIdx.x;
    const int lane = t & 63;
    const int wave = t >> 6;

    // sequential A staging pointers (no gather in hot loop)
    const int srow = t >> 3;
    const int g    = (t & 7) ^ (srow & 7);
    const int n0g  = blockIdx.x * 128;
    const unsigned short* srcA[4];
    const unsigned short* srcB[4];
#pragma unroll
    for (int q = 0; q < 4; ++q) {
        srcA[q] = hbfc + (size_t)(gb + row0 + q * 32 + srow) * DM + g * 8;
        srcB[q] = WeT + ((size_t)e << 20) + (size_t)(n0g + q * 32 + srow) * DM + g * 8;
    }

    EXP_STAGE(0, 0);   // issue before the sTok barrier: staging has no sTok dependency

    if (t < 128) {
        const int idx = row0 + t;
        if (idx < cnt) { sTok[t] = btok[e * NB_TOK + idx]; sWt[t] = bwgt[e * NB_TOK + idx]; }
        else           { sTok[t] = 0;                      sWt[t] = 0.f; }
    }

    const int grp = lane >> 4;
    int offA[2][4], offB[2][4];
#pragma unroll
    for (int ks = 0; ks < 2; ++ks)
#pragma unroll
        for (int m = 0; m < 4; ++m) {
            const int rA = ((wave >> 1) * 64) + m * 16 + (lane & 15);
            const int rB = ((wave & 1) * 64) + m * 16 + (lane & 15);
            const int c  = ks * 4 + grp;
            offA[ks][m] = rA * 128 + (((c ^ (rA & 7)) & 7) << 4);
            offB[ks][m] = rB * 128 + (((c ^ (rB & 7)) & 7) << 4);
        }

    floatx4 acc[4][4];
#pragma unroll
    for (int m = 0; m < 4; ++m)
#pragma unroll
        for (int n = 0; n < 4; ++n) acc[m][n] = (floatx4){0.f, 0.f, 0.f, 0.f};

    int buf = 0;
    for (int kt = 0; kt < DM / 64; ++kt) {
        __syncthreads();
        if (kt + 1 < DM / 64) EXP_STAGE(buf ^ 1, (kt + 1) * 64);
        const char* lA = (const char*)&ldsA[buf][0][0];
        const char* lB = (const char*)&ldsB[buf][0][0];
#pragma unroll
        for (int ks = 0; ks < 2; ++ks) {
            short8 av[4], bv[4];
#pragma unroll
            for (int m = 0; m < 4; ++m) av[m] = *(const short8*)(lA + offA[ks][m]);
#pragma unroll
            for (int n = 0; n < 4; ++n) bv[n] = *(const short8*)(lB + offB[ks][n]);
#pragma unroll
            for (int m = 0; m < 4; ++m)
#pragma unroll
                for (int n = 0; n < 4; ++n)
                    acc[m][n] = __builtin_amdgcn_mfma_f32_16x16x32_bf16(av[m], bv[n], acc[m][n], 0, 0, 0);
        }
        buf ^= 1;
    }

    // epilogue: primary -> out[tok] directly; secondary -> stage2[tok]; no atomics
    const int wr = wave >> 1, wc = wave & 1;
#pragma unroll
    for (int n = 0; n < 4; ++n) {
        const int col  = n0g + wc * 64 + n * 16 + (lane & 15);
        const float bias = bexp[e * DM + col];
#pragma unroll
        for (int m = 0; m < 4; ++m) {
            const int rbase = wr * 64 + m * 16 + (lane >> 4) * 4;
#pragma unroll
            for (int reg = 0; reg < 4; ++reg) {
                const int r = rbase + reg;
                if (row0 + r >= cnt) continue;
                const int raw = sTok[r];
                const int tok = raw & TOKMSK;
                const float v = gelu_f(acc[m][n][reg] + bias) * sWt[r];
                float* dst = (raw & SECBIT) ? stage2 : out;
                dst[(size_t)tok * DM + col] = v;
            }
        }
    }
}

// ---------------- combine: out[tok] += stage2[tok] ----------------
__global__ __launch_bounds__(256) void k_combine(
    const float* __restrict__ stage2, float* __restrict__ out)
{
    const int tok = blockIdx.x;
    const int c   = threadIdx.x * 4;
    const float4 a = *(const float4*)(out    + (size_t)tok * DM + c);
    const float4 b = *(const float4*)(stage2 + (size_t)tok * DM + c);
    float4 o;
    o.x = a.x + b.x; o.y = a.y + b.y; o.z = a.z + b.z; o.w = a.w + b.w;
    *(float4*)(out + (size_t)tok * DM + c) = o;
}

extern "C" void kernel_launch(void* const* d_in, const int* in_sizes, int n_in,
                              void* d_out, int out_size, void* d_ws, size_t ws_size,
                              hipStream_t stream)
{
    const float* f0 = (const float*)d_in[0];
    const float* f1 = (const float*)d_in[1];
    const float* f2 = (const float*)d_in[2];
    const float* Ws = (const float*)d_in[3];
    const float* bs = (const float*)d_in[4];
    const float* Wg = (const float*)d_in[5];
    const float* bg = (const float*)d_in[6];
    const float* We = (const float*)d_in[7];
    const float* be = (const float*)d_in[8];
    float* out = (float*)d_out;

    // ws layout, peak 166MB. steps: 1 splitA, 2 splitB, 3 shared, 4 gate, 5 bucket,
    // 6 prefix, 6.5 gather, 7 wt, 8 expert, 9 combine.
    //  smalls @ 0     (2MB)  [4-9]   (over dead-Ah head)
    //  WeT    @ 2MB   (16MB) [7-8]   (over dead Ah)
    //  hbfc   @ 18MB  (64MB) [6.5-8] (over dead Ah/Al)
    //  stage2 @ 82MB  (64MB) [8-9]   (over dead Al-tail/BhT/BlT/h)
    //  Ah @0 48MB, Al @48 48MB, BhT @96 3MB, BlT @99 3MB  [1-3]
    //  h  @ 102MB (64MB) [3-6.5]
    const size_t MB = 1048576ULL;
    char* base = (char*)d_ws;
    unsigned short* Ah    = (unsigned short*)(base);
    unsigned short* Al    = (unsigned short*)(base + 48 * MB);
    unsigned short* BhT   = (unsigned short*)(base + 96 * MB);
    unsigned short* BlT   = (unsigned short*)(base + 99 * MB);
    float*          h     = (float*)(base + 102 * MB);
    unsigned short* WeT   = (unsigned short*)(base + 2 * MB);
    unsigned short* hbfc  = (unsigned short*)(base + 18 * MB);
    float*          stage2= (float*)(base + 82 * MB);
    int*    counts = (int*)(base);
    int*    basep  = counts + 16;
    int*    btok   = counts + 64;
    float*  bwgt   = (float*)(btok + NEXP * NB_TOK);
    int*    eidx   = (int*)(bwgt + NEXP * NB_TOK);
    float2* w01    = (float2*)(eidx + NB_TOK);

    k_splitA<<<NB_TOK * (KIN / 4) / 256, 256, 0, stream>>>(f0, f1, f2, Ah, Al);          // 1
    k_splitB<<<dim3(DM / 32, KIN / 32), 256, 0, stream>>>(Ws, BhT, BlT);                 // 2
    k_shared_mfma<<<1024, 256, 0, stream>>>(Ah, Al, BhT, BlT, bs, h);                    // 3

    hipMemsetAsync(counts, 0, 16 * sizeof(int), stream);
    k_gate_topk<<<NB_TOK / 4, 256, 0, stream>>>(h, Wg, bg, eidx, w01);                   // 4
    k_bucket<<<NB_TOK / 256, 256, 0, stream>>>(eidx, w01, counts, btok, bwgt);           // 5
    k_prefix<<<1, 64, 0, stream>>>(counts, basep);                                       // 6
    k_gather<<<2 * NB_TOK, 256, 0, stream>>>(h, btok, basep, hbfc);                      // 6.5

    k_wt_bf16<<<dim3(DM / 32, DM / 32, NEXP), 256, 0, stream>>>(We, WeT);                // 7

    k_expert_mfma<<<dim3(DM / 128, NB_TOK / 128, NEXP), 256, 0, stream>>>(               // 8
        hbfc, WeT, be, counts, basep, btok, bwgt, stage2, out);
    k_combine<<<NB_TOK, 256, 0, stream>>>(stage2, out);                                  // 9
}